// Round 1
// baseline (223.403 us; speedup 1.0000x reference)
//
#include <hip/hip_runtime.h>

#define NB 16384
#define NT 512
#define NL 4
#define NH 2
#define NRET (NB*NT*NH)
#define TC 8

// Swap lanes within pairs (lane 2k <-> 2k+1): DPP quad_perm [1,0,3,2] = 0xB1.
// Full VALU rate, unlike ds_swizzle/bpermute (lgkm latency in the serial chain).
__device__ __forceinline__ float swap1(float x) {
  return __int_as_float(__builtin_amdgcn_mov_dpp(__float_as_int(x), 0xB1, 0xF, 0xF, true));
}
// sigmoid(x) = 1/(1+2^(-x*log2e)) : v_mul, v_exp, v_add, v_rcp
__device__ __forceinline__ float sigm(float x) {
  float e = __builtin_amdgcn_exp2f(-1.4426950408889634f * x);
  return __builtin_amdgcn_rcpf(1.0f + e);
}
// tanh(x) = 2/(1+2^(-2x*log2e)) - 1 : v_mul, v_exp, v_add, v_rcp, v_fma
__device__ __forceinline__ float tanh_(float x) {
  float e = __builtin_amdgcn_exp2f(-2.8853900817779268f * x);
  return fmaf(2.0f, __builtin_amdgcn_rcpf(1.0f + e), -1.0f);
}

// 2 lanes per batch element: lane j owns hidden unit j (4 gate rows {2g+j}).
// 64-thread blocks (1 wave = 32 elements), 512 blocks -> 2 waves/CU.
__global__ __launch_bounds__(64) void lstm_k(
    const float* __restrict__ inp, const float* __restrict__ lab,
    const float* __restrict__ Wih, const float* __restrict__ Whh,
    const float* __restrict__ bhh, float* __restrict__ out)
{
  __shared__ __align__(16) float lds[32][TC*NH];  // 2 KB staging: 8 steps x 32 elems x 2
  const int tid = threadIdx.x;
  const int el = tid >> 1, j = tid & 1, jo = j ^ 1;
  const int b0 = blockIdx.x << 5;
  const int b  = b0 + el;

  // Per-lane weights reordered as (own-j coefficient, other-j coefficient) so the
  // gate eval is branch-free: g = b + wio*x_own + wix*x_oth + who*h_own + whx*h_oth
  float wio[NL][4], wix[NL][4], who[NL][4], whx[NL][4], bi[NL][4];
  #pragma unroll
  for (int l = 0; l < NL; ++l) {
    #pragma unroll
    for (int g = 0; g < 4; ++g) {
      const int row = l*8 + g*2 + j;   // torch gate order: rows [i i f f g g o o]
      wio[l][g] = Wih[row*2 + j];
      wix[l][g] = Wih[row*2 + jo];
      who[l][g] = Whh[row*2 + j];
      whx[l][g] = Whh[row*2 + jo];
      bi[l][g]  = bhh[row];
    }
  }

  float h[NL], hp[NL], c[NL];   // own h, partner h (kept via end-of-cell swap), own c
  #pragma unroll
  for (int l = 0; l < NL; ++l) { h[l] = 0.f; hp[l] = 0.f; c[l] = 0.f; }

  float xo = inp[b*NH + j];     // layer-0 input, (own, other) components
  float xx = inp[b*NH + jo];
  float lsum = 0.f;

  for (int t0 = 0; t0 < NT; t0 += TC) {
    #pragma unroll
    for (int tl = 0; tl < TC; ++tl) {
      #pragma unroll
      for (int l = 0; l < NL; ++l) {
        // 4 independent gate chains (depth-4 FMA each) -> latency hidden by ILP
        float g0 = fmaf(wio[l][0], xo, fmaf(wix[l][0], xx, fmaf(who[l][0], h[l], fmaf(whx[l][0], hp[l], bi[l][0]))));
        float g1 = fmaf(wio[l][1], xo, fmaf(wix[l][1], xx, fmaf(who[l][1], h[l], fmaf(whx[l][1], hp[l], bi[l][1]))));
        float g2 = fmaf(wio[l][2], xo, fmaf(wix[l][2], xx, fmaf(who[l][2], h[l], fmaf(whx[l][2], hp[l], bi[l][2]))));
        float g3 = fmaf(wio[l][3], xo, fmaf(wix[l][3], xx, fmaf(who[l][3], h[l], fmaf(whx[l][3], hp[l], bi[l][3]))));
        float pi = sigm(g0), pf = sigm(g1), tg = tanh_(g2), po = sigm(g3);
        c[l] = fmaf(pf, c[l], pi * tg);
        float nh = po * tanh_(c[l]);
        float ns = swap1(nh);        // single DPP swap serves BOTH next-layer input
        h[l] = nh; hp[l] = ns;       // and next-step partner-h for this layer
        xo = nh; xx = ns;            // feeds layer l+1 (and loops back to layer 0)
      }
      lds[el][tl*NH + j] = xo;       // stage layer-3 h_j
    }
    __syncthreads();
    // Coalesced flush: 32 elem-rows x 64B; fuse label read + squared-error.
    const float4* lf = (const float4*)&lds[0][0];
    #pragma unroll
    for (int q = 0; q < 2; ++q) {
      const int f = q*64 + tid;          // 0..127 float4s
      const int e = f >> 2, p = f & 3;
      float4 v = lf[f];
      const size_t base = (size_t)(b0 + e) * (NT*NH) + (size_t)t0*NH;  // 64B-aligned
      const float4* l4 = (const float4*)(lab + base);
      float4* o4 = (float4*)(out + base);
      float4 lv = l4[p];
      o4[p] = v;
      float d0 = v.x - lv.x, d1 = v.y - lv.y, d2 = v.z - lv.z, d3 = v.w - lv.w;
      lsum = fmaf(d0,d0, fmaf(d1,d1, fmaf(d2,d2, fmaf(d3,d3, lsum))));
    }
    __syncthreads();
  }

  // loss: wave reduce -> one atomic per block; mean scaling folded in
  #pragma unroll
  for (int off = 32; off >= 1; off >>= 1)
    lsum += __shfl_xor(lsum, off, 64);
  if (tid == 0)
    atomicAdd(out + NRET, lsum * (1.0f / (float)NRET));
}

extern "C" void kernel_launch(void* const* d_in, const int* in_sizes, int n_in,
                              void* d_out, int out_size, void* d_ws, size_t ws_size,
                              hipStream_t stream) {
  const float* inp = (const float*)d_in[0];
  const float* lab = (const float*)d_in[1];
  const float* Wih = (const float*)d_in[2];
  const float* Whh = (const float*)d_in[3];
  const float* bhh = (const float*)d_in[4];
  float* out = (float*)d_out;
  // loss slot must be re-zeroed every launch (harness does not re-poison)
  hipMemsetAsync(out + NRET, 0, sizeof(float), stream);
  lstm_k<<<NB/32, 64, 0, stream>>>(inp, lab, Wih, Whh, bhh, out);
}

// Round 2
// 198.325 us; speedup vs baseline: 1.1265x; 1.1265x over previous
//
#include <hip/hip_runtime.h>

#define NB 16384
#define NT 512
#define NL 4
#define NH 2
#define NRET (NB*NT*NH)
#define TC 8

// Swap lanes within pairs (lane 2k <-> 2k+1): DPP quad_perm [1,0,3,2] = 0xB1.
__device__ __forceinline__ float swap1(float x) {
  return __int_as_float(__builtin_amdgcn_mov_dpp(__float_as_int(x), 0xB1, 0xF, 0xF, true));
}
__device__ __forceinline__ float rcp1p(float e) {   // 1/(1+e)
  return __builtin_amdgcn_rcpf(1.0f + e);
}

// 2 lanes per batch element; lane j owns hidden unit j.
// launch_bounds(64, 1): we only ever need 2 waves/CU (all 16384 chains are
// resident at 512 waves) -> give the register allocator the full budget so
// the 96 weight/partial floats stay in VGPRs instead of being reloaded
// inside the serial recurrence (R1: VGPR_Count=68 < 80 weight floats).
__global__ __launch_bounds__(64, 1) void lstm_k(
    const float* __restrict__ inp, const float* __restrict__ lab,
    const float* __restrict__ Wih, const float* __restrict__ Whh,
    const float* __restrict__ bhh, float* __restrict__ out)
{
  __shared__ __align__(16) float lds[32][TC*NH];  // 2 KB staging
  const int tid = threadIdx.x;
  const int el = tid >> 1, j = tid & 1, jo = j ^ 1;
  const int b0 = blockIdx.x << 5;
  const int b  = b0 + el;

  const float K1 = 1.4426950408889634f;   // log2(e)
  const float K2 = 2.8853900817779268f;   // 2 log2(e)
  const float K4 = 5.7707801635558536f;   // 4 log2(e)

  // Activation scales folded into weights: sigma rows x(-log2e), tanh row
  // x(-2log2e). Then sigma(g)=rcp(1+exp2(g~)), and c lives in the scaled
  // domain c~ = -2log2e*c so tanh(c) needs no leading multiply either.
  float wio[NL][4], wix[NL][4], who[NL][4], whx[NL][4], bi[NL][4], part[NL][4];
  #pragma unroll
  for (int l = 0; l < NL; ++l) {
    #pragma unroll
    for (int g = 0; g < 4; ++g) {
      const int row = l*8 + g*2 + j;         // torch rows [i i f f g g o o]
      const float s = (g == 2) ? -K2 : -K1;
      wio[l][g] = s * Wih[row*2 + j];
      wix[l][g] = s * Wih[row*2 + jo];
      who[l][g] = s * Whh[row*2 + j];
      whx[l][g] = s * Whh[row*2 + jo];
      bi[l][g]  = s * bhh[row];
      part[l][g] = bi[l][g];                 // h == 0 at t = 0
    }
  }

  float c[NL];                               // scaled-domain cell state
  #pragma unroll
  for (int l = 0; l < NL; ++l) c[l] = 0.f;

  float xo = inp[b*NH + j];
  float xx = inp[b*NH + jo];
  float lsum = 0.f;

  for (int t0 = 0; t0 < NT; t0 += TC) {
    // Prefetch this chunk's labels: ~600 VALU cycles of compute cover the
    // HBM latency, so the flush no longer stalls on vmcnt.
    float4 lv[2];
    #pragma unroll
    for (int q = 0; q < 2; ++q) {
      const int f = q*64 + tid, e = f >> 2, p = f & 3;
      lv[q] = ((const float4*)(lab + (size_t)(b0 + e) * (NT*NH) + (size_t)t0*NH))[p];
    }

    #pragma unroll
    for (int tl = 0; tl < TC; ++tl) {
      #pragma unroll
      for (int l = 0; l < NL; ++l) {
        // part[] holds who*h + whx*hp + b~ from the previous step (full step
        // of scheduling slack). Swap-dependent fma placed LAST so the DPP
        // latency overlaps the own-lane fma.
        float g0 = fmaf(wix[l][0], xx, fmaf(wio[l][0], xo, part[l][0]));
        float g1 = fmaf(wix[l][1], xx, fmaf(wio[l][1], xo, part[l][1]));
        float g2 = fmaf(wix[l][2], xx, fmaf(wio[l][2], xo, part[l][2]));
        float g3 = fmaf(wix[l][3], xx, fmaf(wio[l][3], xo, part[l][3]));
        float pi = rcp1p(__builtin_amdgcn_exp2f(g0));
        float pf = rcp1p(__builtin_amdgcn_exp2f(g1));
        float r2 = rcp1p(__builtin_amdgcn_exp2f(g2));
        float po = rcp1p(__builtin_amdgcn_exp2f(g3));
        float tgs = fmaf(-K4, r2, K2);       // -2log2e * tanh(g)
        c[l] = fmaf(pf, c[l], pi * tgs);
        float rc = rcp1p(__builtin_amdgcn_exp2f(c[l]));
        float po2 = po + po;
        float nh = fmaf(po2, rc, -po);       // h = po * tanh(c)
        float ns = swap1(nh);
        // Next step's h-partials for this layer: scheduled into latency gaps.
        part[l][0] = fmaf(whx[l][0], ns, fmaf(who[l][0], nh, bi[l][0]));
        part[l][1] = fmaf(whx[l][1], ns, fmaf(who[l][1], nh, bi[l][1]));
        part[l][2] = fmaf(whx[l][2], ns, fmaf(who[l][2], nh, bi[l][2]));
        part[l][3] = fmaf(whx[l][3], ns, fmaf(who[l][3], nh, bi[l][3]));
        xo = nh; xx = ns;
      }
      lds[el][tl*NH + j] = xo;               // stage layer-3 h_j
    }
    __syncthreads();
    // Coalesced flush; labels already in registers -> no load stall.
    const float4* lf = (const float4*)&lds[0][0];
    #pragma unroll
    for (int q = 0; q < 2; ++q) {
      const int f = q*64 + tid, e = f >> 2, p = f & 3;
      float4 v = lf[f];
      float4* o4 = (float4*)(out + (size_t)(b0 + e) * (NT*NH) + (size_t)t0*NH);
      o4[p] = v;
      float d0 = v.x - lv[q].x, d1 = v.y - lv[q].y,
            d2 = v.z - lv[q].z, d3 = v.w - lv[q].w;
      lsum = fmaf(d0,d0, fmaf(d1,d1, fmaf(d2,d2, fmaf(d3,d3, lsum))));
    }
    __syncthreads();
  }

  #pragma unroll
  for (int off = 32; off >= 1; off >>= 1)
    lsum += __shfl_xor(lsum, off, 64);
  if (tid == 0)
    atomicAdd(out + NRET, lsum * (1.0f / (float)NRET));
}

extern "C" void kernel_launch(void* const* d_in, const int* in_sizes, int n_in,
                              void* d_out, int out_size, void* d_ws, size_t ws_size,
                              hipStream_t stream) {
  const float* inp = (const float*)d_in[0];
  const float* lab = (const float*)d_in[1];
  const float* Wih = (const float*)d_in[2];
  const float* Whh = (const float*)d_in[3];
  const float* bhh = (const float*)d_in[4];
  float* out = (float*)d_out;
  // loss slot must be re-zeroed every launch (harness does not re-poison)
  hipMemsetAsync(out + NRET, 0, sizeof(float), stream);
  lstm_k<<<NB/32, 64, 0, stream>>>(inp, lab, Wih, Whh, bhh, out);
}